// Round 13
// baseline (116.431 us; speedup 1.0000x reference)
//
#include <hip/hip_runtime.h>
#include <math.h>

#define CIN    64
#define OUTC   64
#define BOT    16
#define KK     9
#define HH     48
#define WW     48
#define LPIX   (HH*WW)
#define WSZ    9216
#define PSZ    1024
#define PREDCH 10304
#define GRPSZ  2576
#define BATCH  2
#define NPX    18          // 3 rows x 6 cols of pixels per block
#define PXS2   1172        // px-stride (ushorts): 64*18 + 20 pad (conflict-free)
#define QS2    1160        // Q px-stride (ushorts): 64*18 + 8 pad
#define DBS    65

typedef __attribute__((ext_vector_type(8))) short short8v;
typedef __attribute__((ext_vector_type(4))) float float4v;

__device__ inline unsigned short f2bf(float f){
    unsigned u = __float_as_uint(f);
    return (unsigned short)((u + 0x7FFFu + ((u>>16)&1u)) >> 16);   // RNE
}

__global__ __launch_bounds__(256) void cvt_wp(const float* __restrict__ Wp,
                                              unsigned short* __restrict__ Wb) {
    const int n = PREDCH * 16;
    for (int i = blockIdx.x * 256 + threadIdx.x; i < n; i += gridDim.x * 256)
        Wb[i] = f2bf(Wp[i]);
}

// Block = 18 px (3x6), grid 256 (1/CU), 1024 threads (16 waves).
// vs dppc19 (R12, 62.8us profiled): R11/R12 established (1) prefetch works,
// (2) the 64-VGPR allocator ceiling is immovable (R3/4/5/11/12), and
// (3) scratch on the critical path costs ~2us/MB here.  R12 still spills
// ~5 MB (WRITE 7424 vs 2304 output).  This round BUYS registers from the
// Y-phase and SPENDS them on full prefetch:
//  - pv4[4] caching (16 VGPRs live across ~4.5 tasks) -> transient per-Mt
//    ds_read_b128 from xtT inside the MFMA loop (4 quad-only addresses,
//    conflict-free broadcast; ~+10 issues/wave/tap, latency-hidden).
//  - apre[2] -> apre[4]: full-depth cross-tap prefetch (R11 mechanism).
// Net live state: -8 VGPRs vs R12 -> full prefetch + zero spill under 64.
__global__ __launch_bounds__(1024) __attribute__((amdgpu_waves_per_eu(4, 4)))
void dppc20(
    const float* __restrict__ x,
    const unsigned short* __restrict__ Wb,
    const float* __restrict__ bp,
    float* __restrict__ out)
{
    __shared__ float          xt[64 * 5 * 8];       // 10240 B  [c][r5][c8]
    __shared__ float          xtT[5 * 8 * 64];      // 10240 B  [r5*8+c8][c]
    __shared__ unsigned short S[2][NPX * PXS2];     // 84384 B  P_t dbuf
    __shared__ unsigned short Qs[NPX * QS2];        // 41760 B  Q [px][o*18+d]
    __shared__ unsigned short Bfs[4 * 2 * 64 * 8];  //  8192 B  pred B-frags [g][nt][lane]
    __shared__ float          dynb[NPX * DBS];      //  4680 B

    const int tid  = threadIdx.x;
    const int wave = tid >> 6;
    const int lane = tid & 63;
    const int quad = lane >> 4;
    const int lrow = lane & 15;

    const int bi = blockIdx.x;
    const int b  = bi >> 7;
    const int r  = bi & 127;
    const int h0 = (r >> 3) * 3;
    const int w0 = (r & 7) * 6;

    // ---- xt load (coalesced global) ----
    const float* xb = x + (size_t)b * CIN * LPIX;
    for (int i = tid; i < 64 * 5 * 8; i += 1024) {
        const int c  = i / 40;
        const int rm = i - c * 40;
        const int hi = h0 - 1 + (rm >> 3);
        const int wi = w0 - 1 + (rm & 7);
        float v = 0.0f;
        if (hi >= 0 && hi < HH && wi >= 0 && wi < WW)
            v = xb[c * LPIX + hi * WW + wi];
        xt[i] = v;
    }
    __syncthreads();

    // ---- waves 0-7: pred B-frags -> LDS (wave-invariant, built once) ----
    if (wave < 8) {
        const int g  = wave >> 1;
        const int nt = wave & 1;
        const int px = nt * 16 + lrow;
        short8v f = (short8v)0;
        if (quad < 2 && px < NPX) {
            const int pr = px / 6, pc = px - 6 * (px / 6);
            #pragma unroll
            for (int j = 0; j < 8; ++j)
                f[j] = (short)f2bf(xt[((g * 16 + quad * 8 + j) * 5 + pr + 1) * 8 + pc + 1]);
        }
        if (quad == 2 && px < NPX) f[0] = (short)0x3F80;   // bf16(1.0) bias slot
        *(short8v*)&Bfs[((g * 2 + nt) * 64 + lane) * 8] = f;
    } else {
        // ---- waves 8-15: transpose xt -> xtT[spatial][c] (for pv b128 reads) ----
        for (int i = tid - 512; i < 64 * 5 * 8; i += 512) {
            const int sp = i >> 6;
            const int c  = i & 63;
            xtT[i] = xt[c * 40 + sp];
        }
    }
    __syncthreads();

    // ---- Q + dyn_b phase (group 3), Q -> Qs as [px][o*18+d] ----
    for (int u = wave; u < 68; u += 16) {
        const int ch0  = WSZ + u * 16;
        const int mych = ch0 + lrow;
        short8v a = (short8v)0;
        if (quad < 2)       a = *(const short8v*)(Wb + (size_t)mych * 16 + quad * 8);
        else if (quad == 2) a[0] = (short)f2bf(bp[mych]);
        #pragma unroll
        for (int nt = 0; nt < 2; ++nt) {
            const short8v bfr = *(const short8v*)&Bfs[((3 * 2 + nt) * 64 + lane) * 8];
            float4v Dv = {0.f, 0.f, 0.f, 0.f};
            Dv = __builtin_amdgcn_mfma_f32_16x16x32_bf16(a, bfr, Dv, 0, 0, 0);
            const int px = nt * 16 + lrow;
            if (px < NPX) {
                if (u < 64) {   // proj region: 4 consecutive ushorts, C-packed b32
                    const unsigned r01 = (unsigned)f2bf(Dv[0]) | ((unsigned)f2bf(Dv[1]) << 16);
                    const unsigned r23 = (unsigned)f2bf(Dv[2]) | ((unsigned)f2bf(Dv[3]) << 16);
                    unsigned short* p = &Qs[px * QS2 + u * 18 + quad * 4];
                    *(unsigned int*)(p)     = r01;
                    *(unsigned int*)(p + 2) = r23;
                } else {        // dyn_b region
                    #pragma unroll
                    for (int rr = 0; rr < 4; ++rr)
                        dynb[px * DBS + (u - 64) * 16 + quad * 4 + rr] = Dv[rr];
                }
            }
        }
    }

    // ---- cross-tap A-fragment prefetch: FULL depth (16 VGPRs, paid for by
    //      dropping pv4 caching) ----
    short8v apre[4];

    #define PRED_PREFETCH(T)                                                          \
    _Pragma("unroll")                                                                 \
    for (int uu = 0; uu < 4; ++uu) {                                                  \
        const int u  = wave + uu * 16;                                                \
        const int d0 = (u >> 4) * 4;                                                  \
        const int c0 = (u & 15) * 4;                                                  \
        const int chmin = d0 * 576 + c0 * 9 + (T);                                    \
        const int mych  = chmin + (lrow & 3) * 576 + (lrow >> 2) * 9;                 \
        short8v a = (short8v)0;                                                       \
        if (quad < 2)       a = *(const short8v*)(Wb + (size_t)mych * 16 + quad * 8); \
        else if (quad == 2) a[0] = (short)f2bf(bp[mych]);                             \
        apre[uu] = a;                                                                 \
    }

    // ---- pred slice for tap t into buf ----
    // Row remap: A-row lrow -> channel chmin + (lrow&3)*576 + (lrow>>2)*9,
    // so Dv[rr] = (d=d0+rr, c=c0+quad): d-consecutive -> C-packed b32 stores.
    #define PASS(GG, NT)                                                              \
        { short8v am = (myg == (GG)) ? a : (short8v)0;                                \
          const short8v bfr = *(const short8v*)&Bfs[(((GG) * 2 + (NT)) * 64 + lane) * 8]; \
          Dv = __builtin_amdgcn_mfma_f32_16x16x32_bf16(am, bfr, Dv, 0, 0, 0); }

    // BODY: shared tail of PRED (group select + MFMA + packed store); `a` in scope.
    #define PRED_BODY(T, BUF)                                                         \
        const int g0  = chmin / GRPSZ;                                                \
        const int g1  = (chmin + 1755) / GRPSZ;                                       \
        const int myg = mych / GRPSZ;                                                 \
        _Pragma("unroll")                                                             \
        for (int nt = 0; nt < 2; ++nt) {                                              \
            float4v Dv = {0.f, 0.f, 0.f, 0.f};                                        \
            if (g0 == 0)      { PASS(0, nt) if (g1 == 1) PASS(1, nt) }                \
            else if (g0 == 1) { PASS(1, nt) if (g1 == 2) PASS(2, nt) }                \
            else if (g0 == 2) { PASS(2, nt) if (g1 == 3) PASS(3, nt) }                \
            else              { PASS(3, nt) }                                         \
            const int px = nt * 16 + lrow;                                            \
            if (px < NPX) {                                                           \
                const unsigned r01 = (unsigned)f2bf(Dv[0]) | ((unsigned)f2bf(Dv[1]) << 16); \
                const unsigned r23 = (unsigned)f2bf(Dv[2]) | ((unsigned)f2bf(Dv[3]) << 16); \
                unsigned short* p = &S[BUF][px * PXS2 + (c0 + quad) * 18 + d0];       \
                *(unsigned int*)(p)     = r01;                                        \
                *(unsigned int*)(p + 2) = r23;                                        \
            }                                                                         \
        }

    // tap-0 PRED: inline loads (prologue, nothing to prefetch from)
    #define PRED_SLICE0(T, BUF)                                                       \
    for (int u = wave; u < 64; u += 16) {                                             \
        const int d0 = (u >> 4) * 4;                                                  \
        const int c0 = (u & 15) * 4;                                                  \
        const int chmin = d0 * 576 + c0 * 9 + (T);                                    \
        const int mych  = chmin + (lrow & 3) * 576 + (lrow >> 2) * 9;                 \
        short8v a = (short8v)0;                                                       \
        if (quad < 2)       a = *(const short8v*)(Wb + (size_t)mych * 16 + quad * 8); \
        else if (quad == 2) a[0] = (short)f2bf(bp[mych]);                             \
        PRED_BODY(T, BUF)                                                             \
    }

    // steady-state PRED: consumes apre (prefetched one tap earlier)
    #define PRED_COMPUTE(T, BUF)                                                      \
    _Pragma("unroll")                                                                 \
    for (int uu = 0; uu < 4; ++uu) {                                                  \
        const int u  = wave + uu * 16;                                                \
        const int d0 = (u >> 4) * 4;                                                  \
        const int c0 = (u & 15) * 4;                                                  \
        const int chmin = d0 * 576 + c0 * 9 + (T);                                    \
        const int mych  = chmin + (lrow & 3) * 576 + (lrow >> 2) * 9;                 \
        short8v a = apre[uu];                                                         \
        PRED_BODY(T, BUF)                                                             \
    }

    PRED_SLICE0(0, 0)
    PRED_PREFETCH(1)
    __syncthreads();   // covers Qs, dynb, S[0]

    // ---- Y-task assignment: 72 (px,Nt) tasks over 16 waves ----
    const int ntask  = (wave < 8) ? 5 : 4;
    const int tstart = (wave < 8) ? 5 * wave : 40 + 4 * (wave - 8);
    float acc[5] = {0.f, 0.f, 0.f, 0.f, 0.f};

    for (int t = 0; t < KK; ++t) {
        const int buf = t & 1;
        if (t < 8) { PRED_COMPUTE(t + 1, (t + 1) & 1) }
        if (t < 7) { PRED_PREFETCH(t + 2) }

        const int tr = t / 3, tc = t - 3 * (t / 3);

        int lastpx = -1;
        int spb = 0;
        short8v Ap[4];
        #pragma unroll
        for (int k = 0; k < 5; ++k) {
            if (k < ntask) {
                const int tau = tstart + k;
                const int px  = tau >> 2;
                const int Nt  = tau & 3;
                const int pr = px / 6, pc = px - 6 * (px / 6);

                if (px != lastpx) {          // wave-uniform branch
                    lastpx = px;
                    #pragma unroll
                    for (int Mt = 0; Mt < 4; ++Mt) {
                        short8v f = (short8v)0;
                        if (quad < 2)
                            f = *(const short8v*)&S[buf][px * PXS2 + (Mt * 16 + lrow) * 18 + quad * 8];
                        Ap[Mt] = f;
                    }
                    spb = ((pr + tr) * 8 + pc + tc) * 64;
                }

                short8v Bqf = (short8v)0;
                if (quad < 2)
                    Bqf = *(const short8v*)&Qs[px * QS2 + (Nt * 16 + lrow) * 18 + quad * 8];

                float nacc = 0.f, dpacc = 0.f;
                #pragma unroll
                for (int Mt = 0; Mt < 4; ++Mt) {
                    // transient pv load (4 quad-only addresses, conflict-free)
                    const float4v pvm = *(const float4v*)&xtT[spb + Mt * 16 + quad * 4];
                    float4v Dv = {0.f, 0.f, 0.f, 0.f};
                    Dv = __builtin_amdgcn_mfma_f32_16x16x32_bf16(Ap[Mt], Bqf, Dv, 0, 0, 0);
                    #pragma unroll
                    for (int rr = 0; rr < 4; ++rr) {
                        nacc  += Dv[rr] * Dv[rr];
                        dpacc += pvm[rr] * Dv[rr];
                    }
                }
                nacc  += __shfl_xor(nacc, 16);  nacc  += __shfl_xor(nacc, 32);
                dpacc += __shfl_xor(dpacc, 16); dpacc += __shfl_xor(dpacc, 32);
                acc[k] += dpacc * rsqrtf(fmaxf(nacc, 1e-24f));
            }
        }
        __syncthreads();
    }

    // ---- write out ----
    if (quad == 0) {
        #pragma unroll
        for (int k = 0; k < 5; ++k) {
            if (k < ntask) {
                const int tau = tstart + k;
                const int px  = tau >> 2;
                const int Nt  = tau & 3;
                const int pr = px / 6, pc = px - 6 * (px / 6);
                const int l  = (h0 + pr) * WW + (w0 + pc);
                const int o  = Nt * 16 + lrow;
                out[((size_t)b * OUTC + o) * LPIX + l] = acc[k] + dynb[px * DBS + o];
            }
        }
    }
}

extern "C" void kernel_launch(void* const* d_in, const int* in_sizes, int n_in,
                              void* d_out, int out_size, void* d_ws, size_t ws_size,
                              hipStream_t stream) {
    const float* x  = (const float*)d_in[0];
    const float* Wp = (const float*)d_in[1];
    const float* bp = (const float*)d_in[2];
    float* out = (float*)d_out;
    unsigned short* Wb = (unsigned short*)d_ws;   // PREDCH*16 bf16 = 330 KB
    (void)in_sizes; (void)n_in; (void)out_size; (void)ws_size;

    hipLaunchKernelGGL(cvt_wp, dim3(160), dim3(256), 0, stream, Wp, Wb);
    hipLaunchKernelGGL(dppc20, dim3(BATCH * 128), dim3(1024), 0, stream, x, Wb, bp, out);
}

// Round 14
// 111.314 us; speedup vs baseline: 1.0460x; 1.0460x over previous
//
#include <hip/hip_runtime.h>
#include <math.h>

#define CIN    64
#define OUTC   64
#define BOT    16
#define KK     9
#define HH     48
#define WW     48
#define LPIX   (HH*WW)
#define WSZ    9216
#define PSZ    1024
#define PREDCH 10304
#define GRPSZ  2576
#define BATCH  2
#define NPX    18          // 3 rows x 6 cols of pixels per block
#define PXS2   1172        // px-stride (ushorts): 64*18 + 20 pad (conflict-free)
#define QS2    1160        // Q px-stride (ushorts): 64*18 + 8 pad
#define DBS    65

typedef __attribute__((ext_vector_type(8))) short short8v;
typedef __attribute__((ext_vector_type(4))) short short4v;
typedef __attribute__((ext_vector_type(4))) float float4v;

__device__ inline unsigned short f2bf(float f){
    unsigned u = __float_as_uint(f);
    return (unsigned short)((u + 0x7FFFu + ((u>>16)&1u)) >> 16);   // RNE
}

// Y-phase MFMA: contraction over d=16 exactly.
// Preferred: K=16 bf16 MFMA (2-VGPR operands; lane layout row=lane&15,
// k=quad*4+i -- same family as the K=32 layout halved, rocWMMA-standard).
// Fallback: zero-extend to the known-good K=32 with d->k bijection
// k=quad*8+i on BOTH operands (permutation cancels in the contraction).
#if __has_builtin(__builtin_amdgcn_mfma_f32_16x16x16bf16_1k)
__device__ __forceinline__ float4v ymfma(short4v a, short4v b, float4v c) {
    return __builtin_amdgcn_mfma_f32_16x16x16bf16_1k(a, b, c, 0, 0, 0);
}
#else
__device__ __forceinline__ float4v ymfma(short4v a, short4v b, float4v c) {
    short8v a8 = {a[0], a[1], a[2], a[3], 0, 0, 0, 0};
    short8v b8 = {b[0], b[1], b[2], b[3], 0, 0, 0, 0};
    return __builtin_amdgcn_mfma_f32_16x16x32_bf16(a8, b8, c, 0, 0, 0);
}
#endif

__global__ __launch_bounds__(256) void cvt_wp(const float* __restrict__ Wp,
                                              unsigned short* __restrict__ Wb) {
    const int n = PREDCH * 16;
    for (int i = blockIdx.x * 256 + threadIdx.x; i < n; i += gridDim.x * 256)
        Wb[i] = f2bf(Wp[i]);
}

// Block = 18 px (3x6), grid 256 (1/CU), 1024 threads (16 waves).
// vs dppc19 (R12, 62.8us champion) / dppc20 (R13, 66.0us, pv-transient too
// expensive): keep R12's pv4 caching + apre[2], but switch the Y-phase MFMA
// from K=32 (half zero-padded: d=16 of 32 k-slots) to K=16:
//  - Ap[4] 16->8 VGPRs, Bqf 4->2: live state ~50 -> fits the immovable
//    64-VGPR ceiling with ZERO spill (R13's win without R13's cost).
//  - A/B loads become all-64-lane b64 (row*18 + quad*4) -- half the LDS
//    bytes, no quad<2 guards / zero-init.
// PRED stays on K=32 (bias rides in the k=16 slot there).  Everything else
// R12-verbatim.
__global__ __launch_bounds__(1024) __attribute__((amdgpu_waves_per_eu(4, 4)))
void dppc21(
    const float* __restrict__ x,
    const unsigned short* __restrict__ Wb,
    const float* __restrict__ bp,
    float* __restrict__ out)
{
    __shared__ float          xt[64 * 5 * 8];       // 10240 B  [c][r5][c8]
    __shared__ float          xtT[5 * 8 * 64];      // 10240 B  [r5*8+c8][c]
    __shared__ unsigned short S[2][NPX * PXS2];     // 84384 B  P_t dbuf
    __shared__ unsigned short Qs[NPX * QS2];        // 41760 B  Q [px][o*18+d]
    __shared__ unsigned short Bfs[4 * 2 * 64 * 8];  //  8192 B  pred B-frags [g][nt][lane]
    __shared__ float          dynb[NPX * DBS];      //  4680 B

    const int tid  = threadIdx.x;
    const int wave = tid >> 6;
    const int lane = tid & 63;
    const int quad = lane >> 4;
    const int lrow = lane & 15;

    const int bi = blockIdx.x;
    const int b  = bi >> 7;
    const int r  = bi & 127;
    const int h0 = (r >> 3) * 3;
    const int w0 = (r & 7) * 6;

    // ---- xt load (coalesced global) ----
    const float* xb = x + (size_t)b * CIN * LPIX;
    for (int i = tid; i < 64 * 5 * 8; i += 1024) {
        const int c  = i / 40;
        const int rm = i - c * 40;
        const int hi = h0 - 1 + (rm >> 3);
        const int wi = w0 - 1 + (rm & 7);
        float v = 0.0f;
        if (hi >= 0 && hi < HH && wi >= 0 && wi < WW)
            v = xb[c * LPIX + hi * WW + wi];
        xt[i] = v;
    }
    __syncthreads();

    // ---- waves 0-7: pred B-frags -> LDS (wave-invariant, built once) ----
    if (wave < 8) {
        const int g  = wave >> 1;
        const int nt = wave & 1;
        const int px = nt * 16 + lrow;
        short8v f = (short8v)0;
        if (quad < 2 && px < NPX) {
            const int pr = px / 6, pc = px - 6 * (px / 6);
            #pragma unroll
            for (int j = 0; j < 8; ++j)
                f[j] = (short)f2bf(xt[((g * 16 + quad * 8 + j) * 5 + pr + 1) * 8 + pc + 1]);
        }
        if (quad == 2 && px < NPX) f[0] = (short)0x3F80;   // bf16(1.0) bias slot
        *(short8v*)&Bfs[((g * 2 + nt) * 64 + lane) * 8] = f;
    } else {
        // ---- waves 8-15: transpose xt -> xtT[spatial][c] (for pv b128 reads) ----
        for (int i = tid - 512; i < 64 * 5 * 8; i += 512) {
            const int sp = i >> 6;
            const int c  = i & 63;
            xtT[i] = xt[c * 40 + sp];
        }
    }
    __syncthreads();

    // ---- Q + dyn_b phase (group 3), Q -> Qs as [px][o*18+d] ----
    for (int u = wave; u < 68; u += 16) {
        const int ch0  = WSZ + u * 16;
        const int mych = ch0 + lrow;
        short8v a = (short8v)0;
        if (quad < 2)       a = *(const short8v*)(Wb + (size_t)mych * 16 + quad * 8);
        else if (quad == 2) a[0] = (short)f2bf(bp[mych]);
        #pragma unroll
        for (int nt = 0; nt < 2; ++nt) {
            const short8v bfr = *(const short8v*)&Bfs[((3 * 2 + nt) * 64 + lane) * 8];
            float4v Dv = {0.f, 0.f, 0.f, 0.f};
            Dv = __builtin_amdgcn_mfma_f32_16x16x32_bf16(a, bfr, Dv, 0, 0, 0);
            const int px = nt * 16 + lrow;
            if (px < NPX) {
                if (u < 64) {   // proj region: 4 consecutive ushorts, C-packed b32
                    const unsigned r01 = (unsigned)f2bf(Dv[0]) | ((unsigned)f2bf(Dv[1]) << 16);
                    const unsigned r23 = (unsigned)f2bf(Dv[2]) | ((unsigned)f2bf(Dv[3]) << 16);
                    unsigned short* p = &Qs[px * QS2 + u * 18 + quad * 4];
                    *(unsigned int*)(p)     = r01;
                    *(unsigned int*)(p + 2) = r23;
                } else {        // dyn_b region
                    #pragma unroll
                    for (int rr = 0; rr < 4; ++rr)
                        dynb[px * DBS + (u - 64) * 16 + quad * 4 + rr] = Dv[rr];
                }
            }
        }
    }

    // ---- cross-tap A-fragment prefetch: depth 2 (8 VGPRs; R12-proven) ----
    short8v apre[2];

    #define PRED_PREFETCH(T)                                                          \
    _Pragma("unroll")                                                                 \
    for (int uu = 0; uu < 2; ++uu) {                                                  \
        const int u  = wave + uu * 16;                                                \
        const int d0 = (u >> 4) * 4;                                                  \
        const int c0 = (u & 15) * 4;                                                  \
        const int chmin = d0 * 576 + c0 * 9 + (T);                                    \
        const int mych  = chmin + (lrow & 3) * 576 + (lrow >> 2) * 9;                 \
        short8v a = (short8v)0;                                                       \
        if (quad < 2)       a = *(const short8v*)(Wb + (size_t)mych * 16 + quad * 8); \
        else if (quad == 2) a[0] = (short)f2bf(bp[mych]);                             \
        apre[uu] = a;                                                                 \
    }

    // ---- pred slice for tap t into buf ----
    // Row remap: A-row lrow -> channel chmin + (lrow&3)*576 + (lrow>>2)*9,
    // so Dv[rr] = (d=d0+rr, c=c0+quad): d-consecutive -> C-packed b32 stores.
    #define PASS(GG, NT)                                                              \
        { short8v am = (myg == (GG)) ? a : (short8v)0;                                \
          const short8v bfr = *(const short8v*)&Bfs[(((GG) * 2 + (NT)) * 64 + lane) * 8]; \
          Dv = __builtin_amdgcn_mfma_f32_16x16x32_bf16(am, bfr, Dv, 0, 0, 0); }

    // BODY: shared tail of PRED (group select + MFMA + packed store); `a` in scope.
    #define PRED_BODY(T, BUF)                                                         \
        const int g0  = chmin / GRPSZ;                                                \
        const int g1  = (chmin + 1755) / GRPSZ;                                       \
        const int myg = mych / GRPSZ;                                                 \
        _Pragma("unroll")                                                             \
        for (int nt = 0; nt < 2; ++nt) {                                              \
            float4v Dv = {0.f, 0.f, 0.f, 0.f};                                        \
            if (g0 == 0)      { PASS(0, nt) if (g1 == 1) PASS(1, nt) }                \
            else if (g0 == 1) { PASS(1, nt) if (g1 == 2) PASS(2, nt) }                \
            else if (g0 == 2) { PASS(2, nt) if (g1 == 3) PASS(3, nt) }                \
            else              { PASS(3, nt) }                                         \
            const int px = nt * 16 + lrow;                                            \
            if (px < NPX) {                                                           \
                const unsigned r01 = (unsigned)f2bf(Dv[0]) | ((unsigned)f2bf(Dv[1]) << 16); \
                const unsigned r23 = (unsigned)f2bf(Dv[2]) | ((unsigned)f2bf(Dv[3]) << 16); \
                unsigned short* p = &S[BUF][px * PXS2 + (c0 + quad) * 18 + d0];       \
                *(unsigned int*)(p)     = r01;                                        \
                *(unsigned int*)(p + 2) = r23;                                        \
            }                                                                         \
        }

    // tap-0 PRED: inline loads (prologue, nothing to prefetch from)
    #define PRED_SLICE0(T, BUF)                                                       \
    for (int u = wave; u < 64; u += 16) {                                             \
        const int d0 = (u >> 4) * 4;                                                  \
        const int c0 = (u & 15) * 4;                                                  \
        const int chmin = d0 * 576 + c0 * 9 + (T);                                    \
        const int mych  = chmin + (lrow & 3) * 576 + (lrow >> 2) * 9;                 \
        short8v a = (short8v)0;                                                       \
        if (quad < 2)       a = *(const short8v*)(Wb + (size_t)mych * 16 + quad * 8); \
        else if (quad == 2) a[0] = (short)f2bf(bp[mych]);                             \
        PRED_BODY(T, BUF)                                                             \
    }

    // steady-state PRED: uu 0-1 consume apre (prefetched one tap earlier);
    // uu 2-3 load inline (stall partially covered by uu 0-1's MFMAs in flight)
    #define PRED_COMPUTE(T, BUF)                                                      \
    _Pragma("unroll")                                                                 \
    for (int uu = 0; uu < 4; ++uu) {                                                  \
        const int u  = wave + uu * 16;                                                \
        const int d0 = (u >> 4) * 4;                                                  \
        const int c0 = (u & 15) * 4;                                                  \
        const int chmin = d0 * 576 + c0 * 9 + (T);                                    \
        const int mych  = chmin + (lrow & 3) * 576 + (lrow >> 2) * 9;                 \
        short8v a;                                                                    \
        if (uu < 2) {                                                                 \
            a = apre[uu];                                                             \
        } else {                                                                      \
            a = (short8v)0;                                                           \
            if (quad < 2)       a = *(const short8v*)(Wb + (size_t)mych * 16 + quad * 8); \
            else if (quad == 2) a[0] = (short)f2bf(bp[mych]);                         \
        }                                                                             \
        PRED_BODY(T, BUF)                                                             \
    }

    PRED_SLICE0(0, 0)
    PRED_PREFETCH(1)
    __syncthreads();   // covers Qs, dynb, S[0]

    // ---- Y-task assignment: 72 (px,Nt) tasks over 16 waves ----
    const int ntask  = (wave < 8) ? 5 : 4;
    const int tstart = (wave < 8) ? 5 * wave : 40 + 4 * (wave - 8);
    float acc[5] = {0.f, 0.f, 0.f, 0.f, 0.f};

    for (int t = 0; t < KK; ++t) {
        const int buf = t & 1;
        if (t < 8) { PRED_COMPUTE(t + 1, (t + 1) & 1) }
        if (t < 7) { PRED_PREFETCH(t + 2) }

        const int tr = t / 3, tc = t - 3 * (t / 3);

        int lastpx = -1;
        short4v Ap[4];                      // K=16 fragments: 2 VGPRs each
        float4v pv4[4];
        #pragma unroll
        for (int k = 0; k < 5; ++k) {
            if (k < ntask) {
                const int tau = tstart + k;
                const int px  = tau >> 2;
                const int Nt  = tau & 3;
                const int pr = px / 6, pc = px - 6 * (px / 6);

                if (px != lastpx) {          // wave-uniform branch
                    lastpx = px;
                    #pragma unroll
                    for (int Mt = 0; Mt < 4; ++Mt)   // all 64 lanes load (k=quad*4+i)
                        Ap[Mt] = *(const short4v*)&S[buf][px * PXS2 + (Mt * 16 + lrow) * 18 + quad * 4];
                    const int spb = ((pr + tr) * 8 + pc + tc) * 64;
                    #pragma unroll
                    for (int Mt = 0; Mt < 4; ++Mt)
                        pv4[Mt] = *(const float4v*)&xtT[spb + Mt * 16 + quad * 4];
                }

                const short4v Bqf = *(const short4v*)&Qs[px * QS2 + (Nt * 16 + lrow) * 18 + quad * 4];

                float nacc = 0.f, dpacc = 0.f;
                #pragma unroll
                for (int Mt = 0; Mt < 4; ++Mt) {
                    float4v Dv = {0.f, 0.f, 0.f, 0.f};
                    Dv = ymfma(Ap[Mt], Bqf, Dv);
                    #pragma unroll
                    for (int rr = 0; rr < 4; ++rr) {
                        nacc  += Dv[rr] * Dv[rr];
                        dpacc += pv4[Mt][rr] * Dv[rr];
                    }
                }
                nacc  += __shfl_xor(nacc, 16);  nacc  += __shfl_xor(nacc, 32);
                dpacc += __shfl_xor(dpacc, 16); dpacc += __shfl_xor(dpacc, 32);
                acc[k] += dpacc * rsqrtf(fmaxf(nacc, 1e-24f));
            }
        }
        __syncthreads();
    }

    // ---- write out ----
    if (quad == 0) {
        #pragma unroll
        for (int k = 0; k < 5; ++k) {
            if (k < ntask) {
                const int tau = tstart + k;
                const int px  = tau >> 2;
                const int Nt  = tau & 3;
                const int pr = px / 6, pc = px - 6 * (px / 6);
                const int l  = (h0 + pr) * WW + (w0 + pc);
                const int o  = Nt * 16 + lrow;
                out[((size_t)b * OUTC + o) * LPIX + l] = acc[k] + dynb[px * DBS + o];
            }
        }
    }
}

extern "C" void kernel_launch(void* const* d_in, const int* in_sizes, int n_in,
                              void* d_out, int out_size, void* d_ws, size_t ws_size,
                              hipStream_t stream) {
    const float* x  = (const float*)d_in[0];
    const float* Wp = (const float*)d_in[1];
    const float* bp = (const float*)d_in[2];
    float* out = (float*)d_out;
    unsigned short* Wb = (unsigned short*)d_ws;   // PREDCH*16 bf16 = 330 KB
    (void)in_sizes; (void)n_in; (void)out_size; (void)ws_size;

    hipLaunchKernelGGL(cvt_wp, dim3(160), dim3(256), 0, stream, Wp, Wb);
    hipLaunchKernelGGL(dppc21, dim3(BATCH * 128), dim3(1024), 0, stream, x, Wb, bp, out);
}

// Round 15
// 110.548 us; speedup vs baseline: 1.0532x; 1.0069x over previous
//
#include <hip/hip_runtime.h>
#include <math.h>

#define CIN    64
#define OUTC   64
#define BOT    16
#define KK     9
#define HH     48
#define WW     48
#define LPIX   (HH*WW)
#define WSZ    9216
#define PSZ    1024
#define PREDCH 10304
#define GRPSZ  2576
#define BATCH  2
#define NPX    18          // 3 rows x 6 cols of pixels per block
#define PXS2   1172        // px-stride (ushorts): 64*18 + 20 pad (conflict-free)
#define QS2    1160        // Q px-stride (ushorts): 64*18 + 8 pad
#define DBS    65

typedef __attribute__((ext_vector_type(8))) short short8v;
typedef __attribute__((ext_vector_type(4))) short short4v;
typedef __attribute__((ext_vector_type(4))) float float4v;

__device__ inline unsigned short f2bf(float f){
    unsigned u = __float_as_uint(f);
    return (unsigned short)((u + 0x7FFFu + ((u>>16)&1u)) >> 16);   // RNE
}

// Y-phase MFMA: contraction over d=16 exactly (verified R14).
#if __has_builtin(__builtin_amdgcn_mfma_f32_16x16x16bf16_1k)
__device__ __forceinline__ float4v ymfma(short4v a, short4v b, float4v c) {
    return __builtin_amdgcn_mfma_f32_16x16x16bf16_1k(a, b, c, 0, 0, 0);
}
#else
__device__ __forceinline__ float4v ymfma(short4v a, short4v b, float4v c) {
    short8v a8 = {a[0], a[1], a[2], a[3], 0, 0, 0, 0};
    short8v b8 = {b[0], b[1], b[2], b[3], 0, 0, 0, 0};
    return __builtin_amdgcn_mfma_f32_16x16x32_bf16(a8, b8, c, 0, 0, 0);
}
#endif

__global__ __launch_bounds__(256) void cvt_wp(const float* __restrict__ Wp,
                                              unsigned short* __restrict__ Wb) {
    const int n = PREDCH * 16;
    for (int i = blockIdx.x * 256 + threadIdx.x; i < n; i += gridDim.x * 256)
        Wb[i] = f2bf(Wp[i]);
}

// Block = 18 px (3x6), grid 256 (1/CU), 1024 threads (16 waves).
// vs dppc21 (R14, 57.8us champion): hoist the tap-INVARIANT Q fragments
// into registers.  Each wave's (px,Nt) task set is identical across all 9
// taps, and Qs is written once (never overwritten), yet Bqf was re-read
// from LDS every tap (~40 ds_read_b64 + addressing per wave; 36 redundant).
// Bq[5] (10 VGPRs, statically indexed) is loaded ONCE after the first
// barrier -- affordable now that K=16 freed ~10 VGPRs (Ap 16->8, Bqf 4->2).
// dppc7's register-caching structure, back under the 64-VGPR ceiling.
// Single mechanism; everything else R14-verbatim.
__global__ __launch_bounds__(1024) __attribute__((amdgpu_waves_per_eu(4, 4)))
void dppc22(
    const float* __restrict__ x,
    const unsigned short* __restrict__ Wb,
    const float* __restrict__ bp,
    float* __restrict__ out)
{
    __shared__ float          xt[64 * 5 * 8];       // 10240 B  [c][r5][c8]
    __shared__ float          xtT[5 * 8 * 64];      // 10240 B  [r5*8+c8][c]
    __shared__ unsigned short S[2][NPX * PXS2];     // 84384 B  P_t dbuf
    __shared__ unsigned short Qs[NPX * QS2];        // 41760 B  Q [px][o*18+d]
    __shared__ unsigned short Bfs[4 * 2 * 64 * 8];  //  8192 B  pred B-frags [g][nt][lane]
    __shared__ float          dynb[NPX * DBS];      //  4680 B

    const int tid  = threadIdx.x;
    const int wave = tid >> 6;
    const int lane = tid & 63;
    const int quad = lane >> 4;
    const int lrow = lane & 15;

    const int bi = blockIdx.x;
    const int b  = bi >> 7;
    const int r  = bi & 127;
    const int h0 = (r >> 3) * 3;
    const int w0 = (r & 7) * 6;

    // ---- xt load (coalesced global) ----
    const float* xb = x + (size_t)b * CIN * LPIX;
    for (int i = tid; i < 64 * 5 * 8; i += 1024) {
        const int c  = i / 40;
        const int rm = i - c * 40;
        const int hi = h0 - 1 + (rm >> 3);
        const int wi = w0 - 1 + (rm & 7);
        float v = 0.0f;
        if (hi >= 0 && hi < HH && wi >= 0 && wi < WW)
            v = xb[c * LPIX + hi * WW + wi];
        xt[i] = v;
    }
    __syncthreads();

    // ---- waves 0-7: pred B-frags -> LDS (wave-invariant, built once) ----
    if (wave < 8) {
        const int g  = wave >> 1;
        const int nt = wave & 1;
        const int px = nt * 16 + lrow;
        short8v f = (short8v)0;
        if (quad < 2 && px < NPX) {
            const int pr = px / 6, pc = px - 6 * (px / 6);
            #pragma unroll
            for (int j = 0; j < 8; ++j)
                f[j] = (short)f2bf(xt[((g * 16 + quad * 8 + j) * 5 + pr + 1) * 8 + pc + 1]);
        }
        if (quad == 2 && px < NPX) f[0] = (short)0x3F80;   // bf16(1.0) bias slot
        *(short8v*)&Bfs[((g * 2 + nt) * 64 + lane) * 8] = f;
    } else {
        // ---- waves 8-15: transpose xt -> xtT[spatial][c] (for pv b128 reads) ----
        for (int i = tid - 512; i < 64 * 5 * 8; i += 512) {
            const int sp = i >> 6;
            const int c  = i & 63;
            xtT[i] = xt[c * 40 + sp];
        }
    }
    __syncthreads();

    // ---- Q + dyn_b phase (group 3), Q -> Qs as [px][o*18+d] ----
    for (int u = wave; u < 68; u += 16) {
        const int ch0  = WSZ + u * 16;
        const int mych = ch0 + lrow;
        short8v a = (short8v)0;
        if (quad < 2)       a = *(const short8v*)(Wb + (size_t)mych * 16 + quad * 8);
        else if (quad == 2) a[0] = (short)f2bf(bp[mych]);
        #pragma unroll
        for (int nt = 0; nt < 2; ++nt) {
            const short8v bfr = *(const short8v*)&Bfs[((3 * 2 + nt) * 64 + lane) * 8];
            float4v Dv = {0.f, 0.f, 0.f, 0.f};
            Dv = __builtin_amdgcn_mfma_f32_16x16x32_bf16(a, bfr, Dv, 0, 0, 0);
            const int px = nt * 16 + lrow;
            if (px < NPX) {
                if (u < 64) {   // proj region: 4 consecutive ushorts, C-packed b32
                    const unsigned r01 = (unsigned)f2bf(Dv[0]) | ((unsigned)f2bf(Dv[1]) << 16);
                    const unsigned r23 = (unsigned)f2bf(Dv[2]) | ((unsigned)f2bf(Dv[3]) << 16);
                    unsigned short* p = &Qs[px * QS2 + u * 18 + quad * 4];
                    *(unsigned int*)(p)     = r01;
                    *(unsigned int*)(p + 2) = r23;
                } else {        // dyn_b region
                    #pragma unroll
                    for (int rr = 0; rr < 4; ++rr)
                        dynb[px * DBS + (u - 64) * 16 + quad * 4 + rr] = Dv[rr];
                }
            }
        }
    }

    // ---- cross-tap A-fragment prefetch: depth 2 (8 VGPRs; R12-proven) ----
    short8v apre[2];

    #define PRED_PREFETCH(T)                                                          \
    _Pragma("unroll")                                                                 \
    for (int uu = 0; uu < 2; ++uu) {                                                  \
        const int u  = wave + uu * 16;                                                \
        const int d0 = (u >> 4) * 4;                                                  \
        const int c0 = (u & 15) * 4;                                                  \
        const int chmin = d0 * 576 + c0 * 9 + (T);                                    \
        const int mych  = chmin + (lrow & 3) * 576 + (lrow >> 2) * 9;                 \
        short8v a = (short8v)0;                                                       \
        if (quad < 2)       a = *(const short8v*)(Wb + (size_t)mych * 16 + quad * 8); \
        else if (quad == 2) a[0] = (short)f2bf(bp[mych]);                             \
        apre[uu] = a;                                                                 \
    }

    // ---- pred slice for tap t into buf ----
    // Row remap: A-row lrow -> channel chmin + (lrow&3)*576 + (lrow>>2)*9,
    // so Dv[rr] = (d=d0+rr, c=c0+quad): d-consecutive -> C-packed b32 stores.
    #define PASS(GG, NT)                                                              \
        { short8v am = (myg == (GG)) ? a : (short8v)0;                                \
          const short8v bfr = *(const short8v*)&Bfs[(((GG) * 2 + (NT)) * 64 + lane) * 8]; \
          Dv = __builtin_amdgcn_mfma_f32_16x16x32_bf16(am, bfr, Dv, 0, 0, 0); }

    // BODY: shared tail of PRED (group select + MFMA + packed store); `a` in scope.
    #define PRED_BODY(T, BUF)                                                         \
        const int g0  = chmin / GRPSZ;                                                \
        const int g1  = (chmin + 1755) / GRPSZ;                                       \
        const int myg = mych / GRPSZ;                                                 \
        _Pragma("unroll")                                                             \
        for (int nt = 0; nt < 2; ++nt) {                                              \
            float4v Dv = {0.f, 0.f, 0.f, 0.f};                                        \
            if (g0 == 0)      { PASS(0, nt) if (g1 == 1) PASS(1, nt) }                \
            else if (g0 == 1) { PASS(1, nt) if (g1 == 2) PASS(2, nt) }                \
            else if (g0 == 2) { PASS(2, nt) if (g1 == 3) PASS(3, nt) }                \
            else              { PASS(3, nt) }                                         \
            const int px = nt * 16 + lrow;                                            \
            if (px < NPX) {                                                           \
                const unsigned r01 = (unsigned)f2bf(Dv[0]) | ((unsigned)f2bf(Dv[1]) << 16); \
                const unsigned r23 = (unsigned)f2bf(Dv[2]) | ((unsigned)f2bf(Dv[3]) << 16); \
                unsigned short* p = &S[BUF][px * PXS2 + (c0 + quad) * 18 + d0];       \
                *(unsigned int*)(p)     = r01;                                        \
                *(unsigned int*)(p + 2) = r23;                                        \
            }                                                                         \
        }

    // tap-0 PRED: inline loads (prologue, nothing to prefetch from)
    #define PRED_SLICE0(T, BUF)                                                       \
    for (int u = wave; u < 64; u += 16) {                                             \
        const int d0 = (u >> 4) * 4;                                                  \
        const int c0 = (u & 15) * 4;                                                  \
        const int chmin = d0 * 576 + c0 * 9 + (T);                                    \
        const int mych  = chmin + (lrow & 3) * 576 + (lrow >> 2) * 9;                 \
        short8v a = (short8v)0;                                                       \
        if (quad < 2)       a = *(const short8v*)(Wb + (size_t)mych * 16 + quad * 8); \
        else if (quad == 2) a[0] = (short)f2bf(bp[mych]);                             \
        PRED_BODY(T, BUF)                                                             \
    }

    // steady-state PRED: uu 0-1 consume apre (prefetched one tap earlier);
    // uu 2-3 load inline (stall partially covered by uu 0-1's MFMAs in flight)
    #define PRED_COMPUTE(T, BUF)                                                      \
    _Pragma("unroll")                                                                 \
    for (int uu = 0; uu < 4; ++uu) {                                                  \
        const int u  = wave + uu * 16;                                                \
        const int d0 = (u >> 4) * 4;                                                  \
        const int c0 = (u & 15) * 4;                                                  \
        const int chmin = d0 * 576 + c0 * 9 + (T);                                    \
        const int mych  = chmin + (lrow & 3) * 576 + (lrow >> 2) * 9;                 \
        short8v a;                                                                    \
        if (uu < 2) {                                                                 \
            a = apre[uu];                                                             \
        } else {                                                                      \
            a = (short8v)0;                                                           \
            if (quad < 2)       a = *(const short8v*)(Wb + (size_t)mych * 16 + quad * 8); \
            else if (quad == 2) a[0] = (short)f2bf(bp[mych]);                         \
        }                                                                             \
        PRED_BODY(T, BUF)                                                             \
    }

    PRED_SLICE0(0, 0)
    PRED_PREFETCH(1)
    __syncthreads();   // covers Qs, dynb, S[0]

    // ---- Y-task assignment: 72 (px,Nt) tasks over 16 waves ----
    const int ntask  = (wave < 8) ? 5 : 4;
    const int tstart = (wave < 8) ? 5 * wave : 40 + 4 * (wave - 8);
    float acc[5] = {0.f, 0.f, 0.f, 0.f, 0.f};

    // ---- hoist tap-invariant Q fragments: one b64 load per task, ONCE ----
    short4v Bq[5];
    #pragma unroll
    for (int k = 0; k < 5; ++k) {
        if (k < ntask) {
            const int tau = tstart + k;
            const int px  = tau >> 2;
            const int Nt  = tau & 3;
            Bq[k] = *(const short4v*)&Qs[px * QS2 + (Nt * 16 + lrow) * 18 + quad * 4];
        } else {
            Bq[k] = (short4v)0;
        }
    }

    for (int t = 0; t < KK; ++t) {
        const int buf = t & 1;
        if (t < 8) { PRED_COMPUTE(t + 1, (t + 1) & 1) }
        if (t < 7) { PRED_PREFETCH(t + 2) }

        const int tr = t / 3, tc = t - 3 * (t / 3);

        int lastpx = -1;
        short4v Ap[4];                      // K=16 fragments: 2 VGPRs each
        float4v pv4[4];
        #pragma unroll
        for (int k = 0; k < 5; ++k) {
            if (k < ntask) {
                const int tau = tstart + k;
                const int px  = tau >> 2;
                const int pr = px / 6, pc = px - 6 * (px / 6);

                if (px != lastpx) {          // wave-uniform branch
                    lastpx = px;
                    #pragma unroll
                    for (int Mt = 0; Mt < 4; ++Mt)   // all 64 lanes load (k=quad*4+i)
                        Ap[Mt] = *(const short4v*)&S[buf][px * PXS2 + (Mt * 16 + lrow) * 18 + quad * 4];
                    const int spb = ((pr + tr) * 8 + pc + tc) * 64;
                    #pragma unroll
                    for (int Mt = 0; Mt < 4; ++Mt)
                        pv4[Mt] = *(const float4v*)&xtT[spb + Mt * 16 + quad * 4];
                }

                float nacc = 0.f, dpacc = 0.f;
                #pragma unroll
                for (int Mt = 0; Mt < 4; ++Mt) {
                    float4v Dv = {0.f, 0.f, 0.f, 0.f};
                    Dv = ymfma(Ap[Mt], Bq[k], Dv);
                    #pragma unroll
                    for (int rr = 0; rr < 4; ++rr) {
                        nacc  += Dv[rr] * Dv[rr];
                        dpacc += pv4[Mt][rr] * Dv[rr];
                    }
                }
                nacc  += __shfl_xor(nacc, 16);  nacc  += __shfl_xor(nacc, 32);
                dpacc += __shfl_xor(dpacc, 16); dpacc += __shfl_xor(dpacc, 32);
                acc[k] += dpacc * rsqrtf(fmaxf(nacc, 1e-24f));
            }
        }
        __syncthreads();
    }

    // ---- write out ----
    if (quad == 0) {
        #pragma unroll
        for (int k = 0; k < 5; ++k) {
            if (k < ntask) {
                const int tau = tstart + k;
                const int px  = tau >> 2;
                const int Nt  = tau & 3;
                const int pr = px / 6, pc = px - 6 * (px / 6);
                const int l  = (h0 + pr) * WW + (w0 + pc);
                const int o  = Nt * 16 + lrow;
                out[((size_t)b * OUTC + o) * LPIX + l] = acc[k] + dynb[px * DBS + o];
            }
        }
    }
}

extern "C" void kernel_launch(void* const* d_in, const int* in_sizes, int n_in,
                              void* d_out, int out_size, void* d_ws, size_t ws_size,
                              hipStream_t stream) {
    const float* x  = (const float*)d_in[0];
    const float* Wp = (const float*)d_in[1];
    const float* bp = (const float*)d_in[2];
    float* out = (float*)d_out;
    unsigned short* Wb = (unsigned short*)d_ws;   // PREDCH*16 bf16 = 330 KB
    (void)in_sizes; (void)n_in; (void)out_size; (void)ws_size;

    hipLaunchKernelGGL(cvt_wp, dim3(160), dim3(256), 0, stream, Wp, Wb);
    hipLaunchKernelGGL(dppc22, dim3(BATCH * 128), dim3(1024), 0, stream, x, Wb, bp, out);
}

// Round 16
// 107.489 us; speedup vs baseline: 1.0832x; 1.0285x over previous
//
#include <hip/hip_runtime.h>
#include <math.h>

#if defined(__has_include)
#if __has_include(<hip/hip_bf16.h>)
#include <hip/hip_bf16.h>
#define HAVE_BF16_H 1
#endif
#endif

#define CIN    64
#define OUTC   64
#define BOT    16
#define KK     9
#define HH     48
#define WW     48
#define LPIX   (HH*WW)
#define WSZ    9216
#define PSZ    1024
#define PREDCH 10304
#define GRPSZ  2576
#define BATCH  2
#define NPX    18          // 3 rows x 6 cols of pixels per block
#define PXS2   1172        // px-stride (ushorts): 64*18 + 20 pad (conflict-free)
#define QS2    1160        // Q px-stride (ushorts): 64*18 + 8 pad
#define DBS    65

typedef __attribute__((ext_vector_type(8))) short short8v;
typedef __attribute__((ext_vector_type(4))) short short4v;
typedef __attribute__((ext_vector_type(4))) float float4v;
typedef __attribute__((ext_vector_type(2))) float float2v;

__device__ inline unsigned short f2bf(float f){
    unsigned u = __float_as_uint(f);
    return (unsigned short)((u + 0x7FFFu + ((u>>16)&1u)) >> 16);   // RNE
}

// Packed f32x2 -> bf16x2 (low = lo).  Native path lowers to
// v_cvt_pk_bf16_f32 (RNE, same rounding as f2bf -> bit-identical output).
// C++-intrinsic only -- NO inline asm (R6 lesson).
__device__ inline unsigned pk2bf(float lo, float hi){
#ifdef HAVE_BF16_H
    __hip_bfloat162 t = __float22bfloat162_rn(float2{lo, hi});
    unsigned r; __builtin_memcpy(&r, &t, 4); return r;
#else
    return (unsigned)f2bf(lo) | ((unsigned)f2bf(hi) << 16);
#endif
}

// Y-phase MFMA: contraction over d=16 exactly (verified R14).
#if __has_builtin(__builtin_amdgcn_mfma_f32_16x16x16bf16_1k)
__device__ __forceinline__ float4v ymfma(short4v a, short4v b, float4v c) {
    return __builtin_amdgcn_mfma_f32_16x16x16bf16_1k(a, b, c, 0, 0, 0);
}
#else
__device__ __forceinline__ float4v ymfma(short4v a, short4v b, float4v c) {
    short8v a8 = {a[0], a[1], a[2], a[3], 0, 0, 0, 0};
    short8v b8 = {b[0], b[1], b[2], b[3], 0, 0, 0, 0};
    return __builtin_amdgcn_mfma_f32_16x16x32_bf16(a8, b8, c, 0, 0, 0);
}
#endif

__global__ __launch_bounds__(256) void cvt_wp(const float* __restrict__ Wp,
                                              unsigned short* __restrict__ Wb) {
    const int n = PREDCH * 16;
    for (int i = blockIdx.x * 256 + threadIdx.x; i < n; i += gridDim.x * 256)
        Wb[i] = f2bf(Wp[i]);
}

// Block = 18 px (3x6), grid 256 (1/CU), 1024 threads (16 waves).
// vs dppc22 (R15, 56.9us champion): two VALU instruction substitutions
// (kernel is VALU-issue-bound: VALUBusy 52%, MfmaUtil 13%, HBM 1.6%):
//  (a) hand-rolled f2bf bit-math packing -> __float22bfloat162_rn
//      (native v_cvt_pk_bf16_f32; ~16 bit-ops+2 OR -> 2 instrs per nt-iter)
//      at PRED store, Q store, Bfs build.  RNE==RNE: bit-identical.
//  (b) nacc/dpacc reduction as float2 vector mul-adds -> v_pk_fma_f32
//      (32 scalar FMA -> 16 packed per task).
// Everything else R15-verbatim.
__global__ __launch_bounds__(1024) __attribute__((amdgpu_waves_per_eu(4, 4)))
void dppc23(
    const float* __restrict__ x,
    const unsigned short* __restrict__ Wb,
    const float* __restrict__ bp,
    float* __restrict__ out)
{
    __shared__ float          xt[64 * 5 * 8];       // 10240 B  [c][r5][c8]
    __shared__ float          xtT[5 * 8 * 64];      // 10240 B  [r5*8+c8][c]
    __shared__ unsigned short S[2][NPX * PXS2];     // 84384 B  P_t dbuf
    __shared__ unsigned short Qs[NPX * QS2];        // 41760 B  Q [px][o*18+d]
    __shared__ unsigned short Bfs[4 * 2 * 64 * 8];  //  8192 B  pred B-frags [g][nt][lane]
    __shared__ float          dynb[NPX * DBS];      //  4680 B

    const int tid  = threadIdx.x;
    const int wave = tid >> 6;
    const int lane = tid & 63;
    const int quad = lane >> 4;
    const int lrow = lane & 15;

    const int bi = blockIdx.x;
    const int b  = bi >> 7;
    const int r  = bi & 127;
    const int h0 = (r >> 3) * 3;
    const int w0 = (r & 7) * 6;

    // ---- xt load (coalesced global) ----
    const float* xb = x + (size_t)b * CIN * LPIX;
    for (int i = tid; i < 64 * 5 * 8; i += 1024) {
        const int c  = i / 40;
        const int rm = i - c * 40;
        const int hi = h0 - 1 + (rm >> 3);
        const int wi = w0 - 1 + (rm & 7);
        float v = 0.0f;
        if (hi >= 0 && hi < HH && wi >= 0 && wi < WW)
            v = xb[c * LPIX + hi * WW + wi];
        xt[i] = v;
    }
    __syncthreads();

    // ---- waves 0-7: pred B-frags -> LDS (wave-invariant, built once) ----
    if (wave < 8) {
        const int g  = wave >> 1;
        const int nt = wave & 1;
        const int px = nt * 16 + lrow;
        unsigned fw[4] = {0u, 0u, 0u, 0u};
        if (quad < 2 && px < NPX) {
            const int pr = px / 6, pc = px - 6 * (px / 6);
            #pragma unroll
            for (int jj = 0; jj < 4; ++jj) {
                const float x0 = xt[((g * 16 + quad * 8 + 2 * jj)     * 5 + pr + 1) * 8 + pc + 1];
                const float x1 = xt[((g * 16 + quad * 8 + 2 * jj + 1) * 5 + pr + 1) * 8 + pc + 1];
                fw[jj] = pk2bf(x0, x1);
            }
        }
        if (quad == 2 && px < NPX) fw[0] = 0x3F80u;   // bf16(1.0) bias slot (low half)
        unsigned* bq = (unsigned*)&Bfs[((g * 2 + nt) * 64 + lane) * 8];
        #pragma unroll
        for (int jj = 0; jj < 4; ++jj) bq[jj] = fw[jj];
    } else {
        // ---- waves 8-15: transpose xt -> xtT[spatial][c] (for pv b128 reads) ----
        for (int i = tid - 512; i < 64 * 5 * 8; i += 512) {
            const int sp = i >> 6;
            const int c  = i & 63;
            xtT[i] = xt[c * 40 + sp];
        }
    }
    __syncthreads();

    // ---- Q + dyn_b phase (group 3), Q -> Qs as [px][o*18+d] ----
    for (int u = wave; u < 68; u += 16) {
        const int ch0  = WSZ + u * 16;
        const int mych = ch0 + lrow;
        short8v a = (short8v)0;
        if (quad < 2)       a = *(const short8v*)(Wb + (size_t)mych * 16 + quad * 8);
        else if (quad == 2) a[0] = (short)f2bf(bp[mych]);
        #pragma unroll
        for (int nt = 0; nt < 2; ++nt) {
            const short8v bfr = *(const short8v*)&Bfs[((3 * 2 + nt) * 64 + lane) * 8];
            float4v Dv = {0.f, 0.f, 0.f, 0.f};
            Dv = __builtin_amdgcn_mfma_f32_16x16x32_bf16(a, bfr, Dv, 0, 0, 0);
            const int px = nt * 16 + lrow;
            if (px < NPX) {
                if (u < 64) {   // proj region: 4 consecutive ushorts, packed b32
                    unsigned short* p = &Qs[px * QS2 + u * 18 + quad * 4];
                    *(unsigned int*)(p)     = pk2bf(Dv[0], Dv[1]);
                    *(unsigned int*)(p + 2) = pk2bf(Dv[2], Dv[3]);
                } else {        // dyn_b region
                    #pragma unroll
                    for (int rr = 0; rr < 4; ++rr)
                        dynb[px * DBS + (u - 64) * 16 + quad * 4 + rr] = Dv[rr];
                }
            }
        }
    }

    // ---- cross-tap A-fragment prefetch: depth 2 (8 VGPRs; R12-proven) ----
    short8v apre[2];

    #define PRED_PREFETCH(T)                                                          \
    _Pragma("unroll")                                                                 \
    for (int uu = 0; uu < 2; ++uu) {                                                  \
        const int u  = wave + uu * 16;                                                \
        const int d0 = (u >> 4) * 4;                                                  \
        const int c0 = (u & 15) * 4;                                                  \
        const int chmin = d0 * 576 + c0 * 9 + (T);                                    \
        const int mych  = chmin + (lrow & 3) * 576 + (lrow >> 2) * 9;                 \
        short8v a = (short8v)0;                                                       \
        if (quad < 2)       a = *(const short8v*)(Wb + (size_t)mych * 16 + quad * 8); \
        else if (quad == 2) a[0] = (short)f2bf(bp[mych]);                             \
        apre[uu] = a;                                                                 \
    }

    // ---- pred slice for tap t into buf ----
    // Row remap: A-row lrow -> channel chmin + (lrow&3)*576 + (lrow>>2)*9,
    // so Dv[rr] = (d=d0+rr, c=c0+quad): d-consecutive -> packed b32 stores.
    #define PASS(GG, NT)                                                              \
        { short8v am = (myg == (GG)) ? a : (short8v)0;                                \
          const short8v bfr = *(const short8v*)&Bfs[(((GG) * 2 + (NT)) * 64 + lane) * 8]; \
          Dv = __builtin_amdgcn_mfma_f32_16x16x32_bf16(am, bfr, Dv, 0, 0, 0); }

    // BODY: shared tail of PRED (group select + MFMA + packed store); `a` in scope.
    #define PRED_BODY(T, BUF)                                                         \
        const int g0  = chmin / GRPSZ;                                                \
        const int g1  = (chmin + 1755) / GRPSZ;                                       \
        const int myg = mych / GRPSZ;                                                 \
        _Pragma("unroll")                                                             \
        for (int nt = 0; nt < 2; ++nt) {                                              \
            float4v Dv = {0.f, 0.f, 0.f, 0.f};                                        \
            if (g0 == 0)      { PASS(0, nt) if (g1 == 1) PASS(1, nt) }                \
            else if (g0 == 1) { PASS(1, nt) if (g1 == 2) PASS(2, nt) }                \
            else if (g0 == 2) { PASS(2, nt) if (g1 == 3) PASS(3, nt) }                \
            else              { PASS(3, nt) }                                         \
            const int px = nt * 16 + lrow;                                            \
            if (px < NPX) {                                                           \
                unsigned short* p = &S[BUF][px * PXS2 + (c0 + quad) * 18 + d0];       \
                *(unsigned int*)(p)     = pk2bf(Dv[0], Dv[1]);                        \
                *(unsigned int*)(p + 2) = pk2bf(Dv[2], Dv[3]);                        \
            }                                                                         \
        }

    // tap-0 PRED: inline loads (prologue, nothing to prefetch from)
    #define PRED_SLICE0(T, BUF)                                                       \
    for (int u = wave; u < 64; u += 16) {                                             \
        const int d0 = (u >> 4) * 4;                                                  \
        const int c0 = (u & 15) * 4;                                                  \
        const int chmin = d0 * 576 + c0 * 9 + (T);                                    \
        const int mych  = chmin + (lrow & 3) * 576 + (lrow >> 2) * 9;                 \
        short8v a = (short8v)0;                                                       \
        if (quad < 2)       a = *(const short8v*)(Wb + (size_t)mych * 16 + quad * 8); \
        else if (quad == 2) a[0] = (short)f2bf(bp[mych]);                             \
        PRED_BODY(T, BUF)                                                             \
    }

    // steady-state PRED: uu 0-1 consume apre (prefetched one tap earlier);
    // uu 2-3 load inline (stall partially covered by uu 0-1's MFMAs in flight)
    #define PRED_COMPUTE(T, BUF)                                                      \
    _Pragma("unroll")                                                                 \
    for (int uu = 0; uu < 4; ++uu) {                                                  \
        const int u  = wave + uu * 16;                                                \
        const int d0 = (u >> 4) * 4;                                                  \
        const int c0 = (u & 15) * 4;                                                  \
        const int chmin = d0 * 576 + c0 * 9 + (T);                                    \
        const int mych  = chmin + (lrow & 3) * 576 + (lrow >> 2) * 9;                 \
        short8v a;                                                                    \
        if (uu < 2) {                                                                 \
            a = apre[uu];                                                             \
        } else {                                                                      \
            a = (short8v)0;                                                           \
            if (quad < 2)       a = *(const short8v*)(Wb + (size_t)mych * 16 + quad * 8); \
            else if (quad == 2) a[0] = (short)f2bf(bp[mych]);                         \
        }                                                                             \
        PRED_BODY(T, BUF)                                                             \
    }

    PRED_SLICE0(0, 0)
    PRED_PREFETCH(1)
    __syncthreads();   // covers Qs, dynb, S[0]

    // ---- Y-task assignment: 72 (px,Nt) tasks over 16 waves ----
    const int ntask  = (wave < 8) ? 5 : 4;
    const int tstart = (wave < 8) ? 5 * wave : 40 + 4 * (wave - 8);
    float acc[5] = {0.f, 0.f, 0.f, 0.f, 0.f};

    // ---- hoist tap-invariant Q fragments: one b64 load per task, ONCE ----
    short4v Bq[5];
    #pragma unroll
    for (int k = 0; k < 5; ++k) {
        if (k < ntask) {
            const int tau = tstart + k;
            const int px  = tau >> 2;
            const int Nt  = tau & 3;
            Bq[k] = *(const short4v*)&Qs[px * QS2 + (Nt * 16 + lrow) * 18 + quad * 4];
        } else {
            Bq[k] = (short4v)0;
        }
    }

    for (int t = 0; t < KK; ++t) {
        const int buf = t & 1;
        if (t < 8) { PRED_COMPUTE(t + 1, (t + 1) & 1) }
        if (t < 7) { PRED_PREFETCH(t + 2) }

        const int tr = t / 3, tc = t - 3 * (t / 3);

        int lastpx = -1;
        short4v Ap[4];                      // K=16 fragments: 2 VGPRs each
        float4v pv4[4];
        #pragma unroll
        for (int k = 0; k < 5; ++k) {
            if (k < ntask) {
                const int tau = tstart + k;
                const int px  = tau >> 2;
                const int pr = px / 6, pc = px - 6 * (px / 6);

                if (px != lastpx) {          // wave-uniform branch
                    lastpx = px;
                    #pragma unroll
                    for (int Mt = 0; Mt < 4; ++Mt)   // all 64 lanes load (k=quad*4+i)
                        Ap[Mt] = *(const short4v*)&S[buf][px * PXS2 + (Mt * 16 + lrow) * 18 + quad * 4];
                    const int spb = ((pr + tr) * 8 + pc + tc) * 64;
                    #pragma unroll
                    for (int Mt = 0; Mt < 4; ++Mt)
                        pv4[Mt] = *(const float4v*)&xtT[spb + Mt * 16 + quad * 4];
                }

                // packed f32x2 reduction (coaxes v_pk_fma_f32)
                float2v n2 = {0.f, 0.f}, d2 = {0.f, 0.f};
                #pragma unroll
                for (int Mt = 0; Mt < 4; ++Mt) {
                    float4v Dv = {0.f, 0.f, 0.f, 0.f};
                    Dv = ymfma(Ap[Mt], Bq[k], Dv);
                    const float2v y0 = {Dv[0], Dv[1]},        y1 = {Dv[2], Dv[3]};
                    const float2v p0 = {pv4[Mt][0], pv4[Mt][1]}, p1 = {pv4[Mt][2], pv4[Mt][3]};
                    n2 = y0 * y0 + n2;  n2 = y1 * y1 + n2;
                    d2 = p0 * y0 + d2;  d2 = p1 * y1 + d2;
                }
                float nacc  = n2[0] + n2[1];
                float dpacc = d2[0] + d2[1];
                nacc  += __shfl_xor(nacc, 16);  nacc  += __shfl_xor(nacc, 32);
                dpacc += __shfl_xor(dpacc, 16); dpacc += __shfl_xor(dpacc, 32);
                acc[k] += dpacc * rsqrtf(fmaxf(nacc, 1e-24f));
            }
        }
        __syncthreads();
    }

    // ---- write out ----
    if (quad == 0) {
        #pragma unroll
        for (int k = 0; k < 5; ++k) {
            if (k < ntask) {
                const int tau = tstart + k;
                const int px  = tau >> 2;
                const int Nt  = tau & 3;
                const int pr = px / 6, pc = px - 6 * (px / 6);
                const int l  = (h0 + pr) * WW + (w0 + pc);
                const int o  = Nt * 16 + lrow;
                out[((size_t)b * OUTC + o) * LPIX + l] = acc[k] + dynb[px * DBS + o];
            }
        }
    }
}

extern "C" void kernel_launch(void* const* d_in, const int* in_sizes, int n_in,
                              void* d_out, int out_size, void* d_ws, size_t ws_size,
                              hipStream_t stream) {
    const float* x  = (const float*)d_in[0];
    const float* Wp = (const float*)d_in[1];
    const float* bp = (const float*)d_in[2];
    float* out = (float*)d_out;
    unsigned short* Wb = (unsigned short*)d_ws;   // PREDCH*16 bf16 = 330 KB
    (void)in_sizes; (void)n_in; (void)out_size; (void)ws_size;

    hipLaunchKernelGGL(cvt_wp, dim3(160), dim3(256), 0, stream, Wp, Wb);
    hipLaunchKernelGGL(dppc23, dim3(BATCH * 128), dim3(1024), 0, stream, x, Wb, bp, out);
}

// Round 17
// 100.113 us; speedup vs baseline: 1.1630x; 1.0737x over previous
//
#include <hip/hip_runtime.h>
#include <math.h>

#if defined(__has_include)
#if __has_include(<hip/hip_bf16.h>)
#include <hip/hip_bf16.h>
#define HAVE_BF16_H 1
#endif
#endif

#define CIN    64
#define OUTC   64
#define BOT    16
#define KK     9
#define HH     48
#define WW     48
#define LPIX   (HH*WW)
#define WSZ    9216
#define PSZ    1024
#define PREDCH 10304
#define GRPSZ  2576
#define BATCH  2
#define NPX    18          // 3 rows x 6 cols of pixels per block
#define PXS2   1172        // px-stride (ushorts): 64*18 + 20 pad (conflict-free)
#define QS2    1160        // Q px-stride (ushorts): 64*18 + 8 pad
#define DBS    65

typedef __attribute__((ext_vector_type(8))) short short8v;
typedef __attribute__((ext_vector_type(4))) short short4v;
typedef __attribute__((ext_vector_type(4))) float float4v;
typedef __attribute__((ext_vector_type(2))) float float2v;

__device__ inline unsigned short f2bf(float f){
    unsigned u = __float_as_uint(f);
    return (unsigned short)((u + 0x7FFFu + ((u>>16)&1u)) >> 16);   // RNE
}

// Packed f32x2 -> bf16x2 (low = lo).  Native path lowers to
// v_cvt_pk_bf16_f32 (RNE, bit-identical to f2bf).  No inline asm (R6).
__device__ inline unsigned pk2bf(float lo, float hi){
#ifdef HAVE_BF16_H
    __hip_bfloat162 t = __float22bfloat162_rn(float2{lo, hi});
    unsigned r; __builtin_memcpy(&r, &t, 4); return r;
#else
    return (unsigned)f2bf(lo) | ((unsigned)f2bf(hi) << 16);
#endif
}

// K=16 bf16 MFMA (2-VGPR operands; lane: row=lane&15, k=quad*4+i).
// Verified numerically in R14/R15/R16.  Fallback zero-extends to K=32.
#if __has_builtin(__builtin_amdgcn_mfma_f32_16x16x16bf16_1k)
__device__ __forceinline__ float4v ymfma(short4v a, short4v b, float4v c) {
    return __builtin_amdgcn_mfma_f32_16x16x16bf16_1k(a, b, c, 0, 0, 0);
}
#else
__device__ __forceinline__ float4v ymfma(short4v a, short4v b, float4v c) {
    short8v a8 = {a[0], a[1], a[2], a[3], 0, 0, 0, 0};
    short8v b8 = {b[0], b[1], b[2], b[3], 0, 0, 0, 0};
    return __builtin_amdgcn_mfma_f32_16x16x32_bf16(a8, b8, c, 0, 0, 0);
}
#endif

__global__ __launch_bounds__(256) void cvt_wp(const float* __restrict__ Wp,
                                              unsigned short* __restrict__ Wb) {
    const int n = PREDCH * 16;
    for (int i = blockIdx.x * 256 + threadIdx.x; i < n; i += gridDim.x * 256)
        Wb[i] = f2bf(Wp[i]);
}

// Block = 18 px (3x6), grid 256 (1/CU), 1024 threads (16 waves).
// vs dppc23 (R16, 53.7us champion): PRED/Q pipeline converted from K=32
// MFMA (only 17/32 k-slots live: 16 weights + bias; quad-divergent setup)
// to the K=16 MFMA Y already uses:
//  - PRED MFMA issue ~halves (no dead k-slots);
//  - all quad<2/quad==2 guards gone: every lane loads short4v weights
//    (Wb + mych*16 + quad*4); Bfs 8->4 KB, all-lane b64 reads; apre 8->4
//    VGPRs;
//  - bias moves to 4 explicit f32 adds per nt: D-row m=quad*4+rr maps to
//    channel chmin + rr*576 + quad*9 (same R8-verified remap algebra);
//    4 independent L2-hit bp loads per u-iter, hoisted, latency-hidden.
// Everything else R16-verbatim.
__global__ __launch_bounds__(1024) __attribute__((amdgpu_waves_per_eu(4, 4)))
void dppc24(
    const float* __restrict__ x,
    const unsigned short* __restrict__ Wb,
    const float* __restrict__ bp,
    float* __restrict__ out)
{
    __shared__ float          xt[64 * 5 * 8];       // 10240 B  [c][r5][c8]
    __shared__ float          xtT[5 * 8 * 64];      // 10240 B  [r5*8+c8][c]
    __shared__ unsigned short S[2][NPX * PXS2];     // 84384 B  P_t dbuf
    __shared__ unsigned short Qs[NPX * QS2];        // 41760 B  Q [px][o*18+d]
    __shared__ unsigned short Bfs[4 * 2 * 64 * 4];  //  4096 B  pred B-frags [g][nt][lane][4]
    __shared__ float          dynb[NPX * DBS];      //  4680 B

    const int tid  = threadIdx.x;
    const int wave = tid >> 6;
    const int lane = tid & 63;
    const int quad = lane >> 4;
    const int lrow = lane & 15;

    const int bi = blockIdx.x;
    const int b  = bi >> 7;
    const int r  = bi & 127;
    const int h0 = (r >> 3) * 3;
    const int w0 = (r & 7) * 6;

    // ---- xt load (coalesced global) ----
    const float* xb = x + (size_t)b * CIN * LPIX;
    for (int i = tid; i < 64 * 5 * 8; i += 1024) {
        const int c  = i / 40;
        const int rm = i - c * 40;
        const int hi = h0 - 1 + (rm >> 3);
        const int wi = w0 - 1 + (rm & 7);
        float v = 0.0f;
        if (hi >= 0 && hi < HH && wi >= 0 && wi < WW)
            v = xb[c * LPIX + hi * WW + wi];
        xt[i] = v;
    }
    __syncthreads();

    // ---- waves 0-7: pred B-frags -> LDS (K=16 layout: c = g*16+quad*4+i) ----
    if (wave < 8) {
        const int g  = wave >> 1;
        const int nt = wave & 1;
        const int px = nt * 16 + lrow;
        unsigned fw[2] = {0u, 0u};
        if (px < NPX) {
            const int pr = px / 6, pc = px - 6 * (px / 6);
            #pragma unroll
            for (int jj = 0; jj < 2; ++jj) {
                const float x0 = xt[((g * 16 + quad * 4 + 2 * jj)     * 5 + pr + 1) * 8 + pc + 1];
                const float x1 = xt[((g * 16 + quad * 4 + 2 * jj + 1) * 5 + pr + 1) * 8 + pc + 1];
                fw[jj] = pk2bf(x0, x1);
            }
        }
        unsigned* bq = (unsigned*)&Bfs[((g * 2 + nt) * 64 + lane) * 4];
        bq[0] = fw[0]; bq[1] = fw[1];
    } else {
        // ---- waves 8-15: transpose xt -> xtT[spatial][c] (for pv b128 reads) ----
        for (int i = tid - 512; i < 64 * 5 * 8; i += 512) {
            const int sp = i >> 6;
            const int c  = i & 63;
            xtT[i] = xt[c * 40 + sp];
        }
    }
    __syncthreads();

    // ---- Q + dyn_b phase (group 3), K=16 + explicit f32 bias ----
    for (int u = wave; u < 68; u += 16) {
        const int ch0  = WSZ + u * 16;
        const int mych = ch0 + lrow;
        const short4v a = *(const short4v*)(Wb + (size_t)mych * 16 + quad * 4);
        float bpv[4];
        #pragma unroll
        for (int rr = 0; rr < 4; ++rr) bpv[rr] = bp[ch0 + quad * 4 + rr];
        #pragma unroll
        for (int nt = 0; nt < 2; ++nt) {
            const short4v bfr = *(const short4v*)&Bfs[((3 * 2 + nt) * 64 + lane) * 4];
            float4v Dv = {0.f, 0.f, 0.f, 0.f};
            Dv = ymfma(a, bfr, Dv);
            const int px = nt * 16 + lrow;
            if (px < NPX) {
                if (u < 64) {   // proj region: 4 consecutive ushorts, packed b32
                    unsigned short* p = &Qs[px * QS2 + u * 18 + quad * 4];
                    *(unsigned int*)(p)     = pk2bf(Dv[0] + bpv[0], Dv[1] + bpv[1]);
                    *(unsigned int*)(p + 2) = pk2bf(Dv[2] + bpv[2], Dv[3] + bpv[3]);
                } else {        // dyn_b region
                    #pragma unroll
                    for (int rr = 0; rr < 4; ++rr)
                        dynb[px * DBS + (u - 64) * 16 + quad * 4 + rr] = Dv[rr] + bpv[rr];
                }
            }
        }
    }

    // ---- cross-tap A-fragment prefetch: depth 2, K=16 frags (4 VGPRs) ----
    short4v apre[2];

    #define PRED_PREFETCH(T)                                                          \
    _Pragma("unroll")                                                                 \
    for (int uu = 0; uu < 2; ++uu) {                                                  \
        const int u  = wave + uu * 16;                                                \
        const int d0 = (u >> 4) * 4;                                                  \
        const int c0 = (u & 15) * 4;                                                  \
        const int chmin = d0 * 576 + c0 * 9 + (T);                                    \
        const int mych  = chmin + (lrow & 3) * 576 + (lrow >> 2) * 9;                 \
        apre[uu] = *(const short4v*)(Wb + (size_t)mych * 16 + quad * 4);              \
    }

    // ---- pred slice for tap t into buf (K=16 MFMA + f32 bias add) ----
    // Row remap: A-row lrow -> channel chmin + (lrow&3)*576 + (lrow>>2)*9,
    // so Dv[rr] = (d=d0+rr, c=c0+quad); bias channel = chmin + rr*576 + quad*9.
    #define PASS(GG, NT)                                                              \
        { short4v am = (myg == (GG)) ? a : (short4v)0;                                \
          const short4v bfr = *(const short4v*)&Bfs[(((GG) * 2 + (NT)) * 64 + lane) * 4]; \
          Dv = ymfma(am, bfr, Dv); }

    #define PRED_BODY(T, BUF)                                                         \
        const int g0  = chmin / GRPSZ;                                                \
        const int g1  = (chmin + 1755) / GRPSZ;                                       \
        const int myg = mych / GRPSZ;                                                 \
        float bpv[4];                                                                 \
        _Pragma("unroll")                                                             \
        for (int rr = 0; rr < 4; ++rr) bpv[rr] = bp[chmin + rr * 576 + quad * 9];     \
        _Pragma("unroll")                                                             \
        for (int nt = 0; nt < 2; ++nt) {                                              \
            float4v Dv = {0.f, 0.f, 0.f, 0.f};                                        \
            if (g0 == 0)      { PASS(0, nt) if (g1 == 1) PASS(1, nt) }                \
            else if (g0 == 1) { PASS(1, nt) if (g1 == 2) PASS(2, nt) }                \
            else if (g0 == 2) { PASS(2, nt) if (g1 == 3) PASS(3, nt) }                \
            else              { PASS(3, nt) }                                         \
            const int px = nt * 16 + lrow;                                            \
            if (px < NPX) {                                                           \
                unsigned short* p = &S[BUF][px * PXS2 + (c0 + quad) * 18 + d0];       \
                *(unsigned int*)(p)     = pk2bf(Dv[0] + bpv[0], Dv[1] + bpv[1]);      \
                *(unsigned int*)(p + 2) = pk2bf(Dv[2] + bpv[2], Dv[3] + bpv[3]);      \
            }                                                                         \
        }

    // tap-0 PRED: inline loads (prologue, nothing to prefetch from)
    #define PRED_SLICE0(T, BUF)                                                       \
    for (int u = wave; u < 64; u += 16) {                                             \
        const int d0 = (u >> 4) * 4;                                                  \
        const int c0 = (u & 15) * 4;                                                  \
        const int chmin = d0 * 576 + c0 * 9 + (T);                                    \
        const int mych  = chmin + (lrow & 3) * 576 + (lrow >> 2) * 9;                 \
        const short4v a = *(const short4v*)(Wb + (size_t)mych * 16 + quad * 4);       \
        PRED_BODY(T, BUF)                                                             \
    }

    // steady-state PRED: uu 0-1 consume apre; uu 2-3 load inline
    #define PRED_COMPUTE(T, BUF)                                                      \
    _Pragma("unroll")                                                                 \
    for (int uu = 0; uu < 4; ++uu) {                                                  \
        const int u  = wave + uu * 16;                                                \
        const int d0 = (u >> 4) * 4;                                                  \
        const int c0 = (u & 15) * 4;                                                  \
        const int chmin = d0 * 576 + c0 * 9 + (T);                                    \
        const int mych  = chmin + (lrow & 3) * 576 + (lrow >> 2) * 9;                 \
        short4v a;                                                                    \
        if (uu < 2) a = apre[uu];                                                     \
        else        a = *(const short4v*)(Wb + (size_t)mych * 16 + quad * 4);         \
        PRED_BODY(T, BUF)                                                             \
    }

    PRED_SLICE0(0, 0)
    PRED_PREFETCH(1)
    __syncthreads();   // covers Qs, dynb, S[0]

    // ---- Y-task assignment: 72 (px,Nt) tasks over 16 waves ----
    const int ntask  = (wave < 8) ? 5 : 4;
    const int tstart = (wave < 8) ? 5 * wave : 40 + 4 * (wave - 8);
    float acc[5] = {0.f, 0.f, 0.f, 0.f, 0.f};

    // ---- hoist tap-invariant Q fragments: one b64 load per task, ONCE ----
    short4v Bq[5];
    #pragma unroll
    for (int k = 0; k < 5; ++k) {
        if (k < ntask) {
            const int tau = tstart + k;
            const int px  = tau >> 2;
            const int Nt  = tau & 3;
            Bq[k] = *(const short4v*)&Qs[px * QS2 + (Nt * 16 + lrow) * 18 + quad * 4];
        } else {
            Bq[k] = (short4v)0;
        }
    }

    for (int t = 0; t < KK; ++t) {
        const int buf = t & 1;
        if (t < 8) { PRED_COMPUTE(t + 1, (t + 1) & 1) }
        if (t < 7) { PRED_PREFETCH(t + 2) }

        const int tr = t / 3, tc = t - 3 * (t / 3);

        int lastpx = -1;
        short4v Ap[4];                      // K=16 fragments: 2 VGPRs each
        float4v pv4[4];
        #pragma unroll
        for (int k = 0; k < 5; ++k) {
            if (k < ntask) {
                const int tau = tstart + k;
                const int px  = tau >> 2;
                const int pr = px / 6, pc = px - 6 * (px / 6);

                if (px != lastpx) {          // wave-uniform branch
                    lastpx = px;
                    #pragma unroll
                    for (int Mt = 0; Mt < 4; ++Mt)   // all 64 lanes load (k=quad*4+i)
                        Ap[Mt] = *(const short4v*)&S[buf][px * PXS2 + (Mt * 16 + lrow) * 18 + quad * 4];
                    const int spb = ((pr + tr) * 8 + pc + tc) * 64;
                    #pragma unroll
                    for (int Mt = 0; Mt < 4; ++Mt)
                        pv4[Mt] = *(const float4v*)&xtT[spb + Mt * 16 + quad * 4];
                }

                // packed f32x2 reduction (v_pk_fma_f32)
                float2v n2 = {0.f, 0.f}, d2 = {0.f, 0.f};
                #pragma unroll
                for (int Mt = 0; Mt < 4; ++Mt) {
                    float4v Dv = {0.f, 0.f, 0.f, 0.f};
                    Dv = ymfma(Ap[Mt], Bq[k], Dv);
                    const float2v y0 = {Dv[0], Dv[1]},        y1 = {Dv[2], Dv[3]};
                    const float2v p0 = {pv4[Mt][0], pv4[Mt][1]}, p1 = {pv4[Mt][2], pv4[Mt][3]};
                    n2 = y0 * y0 + n2;  n2 = y1 * y1 + n2;
                    d2 = p0 * y0 + d2;  d2 = p1 * y1 + d2;
                }
                float nacc  = n2[0] + n2[1];
                float dpacc = d2[0] + d2[1];
                nacc  += __shfl_xor(nacc, 16);  nacc  += __shfl_xor(nacc, 32);
                dpacc += __shfl_xor(dpacc, 16); dpacc += __shfl_xor(dpacc, 32);
                acc[k] += dpacc * rsqrtf(fmaxf(nacc, 1e-24f));
            }
        }
        __syncthreads();
    }

    // ---- write out ----
    if (quad == 0) {
        #pragma unroll
        for (int k = 0; k < 5; ++k) {
            if (k < ntask) {
                const int tau = tstart + k;
                const int px  = tau >> 2;
                const int Nt  = tau & 3;
                const int pr = px / 6, pc = px - 6 * (px / 6);
                const int l  = (h0 + pr) * WW + (w0 + pc);
                const int o  = Nt * 16 + lrow;
                out[((size_t)b * OUTC + o) * LPIX + l] = acc[k] + dynb[px * DBS + o];
            }
        }
    }
}

extern "C" void kernel_launch(void* const* d_in, const int* in_sizes, int n_in,
                              void* d_out, int out_size, void* d_ws, size_t ws_size,
                              hipStream_t stream) {
    const float* x  = (const float*)d_in[0];
    const float* Wp = (const float*)d_in[1];
    const float* bp = (const float*)d_in[2];
    float* out = (float*)d_out;
    unsigned short* Wb = (unsigned short*)d_ws;   // PREDCH*16 bf16 = 330 KB
    (void)in_sizes; (void)n_in; (void)out_size; (void)ws_size;

    hipLaunchKernelGGL(cvt_wp, dim3(160), dim3(256), 0, stream, Wp, Wb);
    hipLaunchKernelGGL(dppc24, dim3(BATCH * 128), dim3(1024), 0, stream, x, Wb, bp, out);
}